// Round 1
// baseline (1056.696 us; speedup 1.0000x reference)
//
#include <hip/hip_runtime.h>
#include <hip/hip_bf16.h>

#define NN 50000
#define DD 128
#define DEF 32
#define EE 500000
#define NET 5
#define KP 832        // padded K (805 real: 5*128 H | 5*32 EF | 5 mask/bias)
#define CHUNKS 196    // ceil(50000/256)

typedef unsigned short u16;
typedef unsigned int u32;
using short8 = __attribute__((ext_vector_type(8))) short;
using f32x4  = __attribute__((ext_vector_type(4))) float;

__device__ __forceinline__ u16 f2bf(float f){
  union { float f; u32 u; } v; v.f = f;
  u32 r = v.u + 0x7FFFu + ((v.u >> 16) & 1u);
  return (u16)(r >> 16);
}

// ---------------- CSR build ----------------
__global__ void k_hist(const int* d0,const int* d1,const int* d2,const int* d3,const int* d4,
                       int* __restrict__ deg){
  int et = blockIdx.y;
  const int* dp = et==0?d0:et==1?d1:et==2?d2:et==3?d3:d4;
  int i = blockIdx.x*256 + threadIdx.x;
  if (i < EE) atomicAdd(&deg[et*NN + dp[i]], 1);
}

__global__ void k_chunksum(const int* __restrict__ deg, int* __restrict__ cs){
  int et = blockIdx.y;
  int i = blockIdx.x*256 + threadIdx.x;
  int x = (i < NN) ? deg[et*NN + i] : 0;
  #pragma unroll
  for (int d = 32; d >= 1; d >>= 1) x += __shfl_down(x, d, 64);
  __shared__ int ws4[4];
  int lane = threadIdx.x & 63, w = threadIdx.x >> 6;
  if (lane == 0) ws4[w] = x;
  __syncthreads();
  if (threadIdx.x == 0) cs[et*CHUNKS + blockIdx.x] = ws4[0]+ws4[1]+ws4[2]+ws4[3];
}

__global__ void k_scanchunks(int* cs){
  int et = blockIdx.x;
  int lane = threadIdx.x;   // block = 64
  int run = 0;
  for (int c0 = 0; c0 < CHUNKS; c0 += 64){
    int i = c0 + lane;
    int x = (i < CHUNKS) ? cs[et*CHUNKS + i] : 0;
    int own = x;
    #pragma unroll
    for (int d = 1; d < 64; d <<= 1){ int y = __shfl_up(x, d, 64); if (lane >= d) x += y; }
    int tot = __shfl(x, 63, 64);
    if (i < CHUNKS) cs[et*CHUNKS + i] = run + x - own;
    run += tot;
  }
}

__global__ void k_localscan(const int* __restrict__ deg, const int* __restrict__ cs,
                            int* __restrict__ off, int* __restrict__ cur){
  int et = blockIdx.y;
  int i = blockIdx.x*256 + threadIdx.x;
  int lane = threadIdx.x & 63, w = threadIdx.x >> 6;
  int x = (i < NN) ? deg[et*NN + i] : 0;
  int own = x;
  #pragma unroll
  for (int d = 1; d < 64; d <<= 1){ int y = __shfl_up(x, d, 64); if (lane >= d) x += y; }
  __shared__ int ws4[4];
  if (lane == 63) ws4[w] = x;
  __syncthreads();
  int add = cs[et*CHUNKS + blockIdx.x];
  for (int k = 0; k < w; k++) add += ws4[k];
  if (i < NN){ int ex = x - own + add; off[et*NN+i] = ex; cur[et*NN+i] = ex; }
}

__global__ void k_scatter(const int* d0,const int* d1,const int* d2,const int* d3,const int* d4,
                          int* __restrict__ cur, int* __restrict__ elist){
  int et = blockIdx.y;
  const int* dp = et==0?d0:et==1?d1:et==2?d2:et==3?d3:d4;
  int i = blockIdx.x*256 + threadIdx.x;
  if (i < EE){
    int d = dp[i];
    int pos = atomicAdd(&cur[et*NN + d], 1);
    elist[(size_t)et*EE + pos] = i;
  }
}

// ------------- per-(etype,node) mean gather → bf16 A row slice -------------
__global__ __launch_bounds__(256) void k_gather(
    const float* __restrict__ opf,
    const float* e0,const float* e1,const float* e2,const float* e3,const float* e4,
    const int* s0,const int* s1,const int* s2,const int* s3,const int* s4,
    const int* __restrict__ off, const int* __restrict__ deg,
    const int* __restrict__ elist, u16* __restrict__ A)
{
  int et = blockIdx.y;
  const float* efp = et==0?e0:et==1?e1:et==2?e2:et==3?e3:e4;
  const int*  srcp = et==0?s0:et==1?s1:et==2?s2:et==3?s3:s4;
  int tid = threadIdx.x;
  int lane = tid & 63, w = tid >> 6;
  int v = blockIdx.x*4 + w;               // grid.x = NN/4 -> v < NN exactly
  int base = off[et*NN + v];
  int dg   = deg[et*NN + v];
  const int* el = elist + (size_t)et*EE + base;
  float h0 = 0.f, h1 = 0.f, efa = 0.f;
  int en = 0, sn = 0;
  if (dg > 0){ en = el[0]; sn = srcp[en]; }
  for (int i = 0; i < dg; i++){
    int e = en, s = sn;
    if (i+1 < dg){ en = el[i+1]; sn = srcp[en]; }   // prefetch next chain
    float2 hv = *(const float2*)(opf + (size_t)s*DD + 2*lane);
    if (lane < DEF) efa += efp[(size_t)e*DEF + lane];
    h0 += hv.x; h1 += hv.y;
  }
  float sc = dg > 0 ? 1.0f/(float)dg : 0.0f;
  u32 pk = (u32)f2bf(h0*sc) | ((u32)f2bf(h1*sc) << 16);
  *(u32*)(A + (size_t)v*KP + et*DD + 2*lane) = pk;
  if (lane < DEF) A[(size_t)v*KP + 640 + et*DEF + lane] = f2bf(efa*sc);
  if (lane == 0)  A[(size_t)v*KP + 800 + et] = dg > 0 ? (u16)0x3F80 : (u16)0;
}

// ------------- build Bt[j][k] (bf16, transposed, pad rows zeroed) -------------
__global__ void k_convB(const float* W0,const float* W1,const float* W2,const float* W3,const float* W4,
                        const float* b0,const float* b1,const float* b2,const float* b3,const float* b4,
                        u16* __restrict__ Bt){
  int id = blockIdx.x*256 + threadIdx.x;
  if (id >= DD*KP) return;
  int j = id / KP, k = id - j*KP;
  const float* Ws[NET] = {W0,W1,W2,W3,W4};
  const float* bs[NET] = {b0,b1,b2,b3,b4};
  float val = 0.f;
  if (k < 640)      { int et = k >> 7, r = k & 127; val = Ws[et][r*DD + j]; }
  else if (k < 800) { int q = k - 640; int et = q >> 5, r = q & 31; val = Ws[et][(DD + r)*DD + j]; }
  else if (k < 805) { val = bs[k - 800][j]; }
  Bt[(size_t)j*KP + k] = f2bf(val);
}

// ------------- fused GEMM + /5 + residual + ReLU -------------
__global__ __launch_bounds__(256) void k_gemm(const u16* __restrict__ A, const u16* __restrict__ Bt,
                                              const float* __restrict__ opf, float* __restrict__ out){
  __shared__ __align__(16) u16 As[64][40];    // +8 pad: bank-conflict break, 16B-aligned rows
  __shared__ __align__(16) u16 Bs[128][40];
  int tid = threadIdx.x, lane = tid & 63, w = tid >> 6;
  int m0 = blockIdx.x * 64;
  f32x4 acc[8];
  #pragma unroll
  for (int nt = 0; nt < 8; nt++) acc[nt] = (f32x4){0.f,0.f,0.f,0.f};

  for (int kt = 0; kt < 26; kt++){
    int k0 = kt * 32;
    { // stage A tile: 64x32 bf16, 1 x 16B per thread
      int r = tid >> 2, c = tid & 3, row = m0 + r;
      uint4 val = {0u,0u,0u,0u};
      if (row < NN) val = *(const uint4*)(A + (size_t)row*KP + k0 + c*8);
      *(uint4*)(&As[r][c*8]) = val;
    }
    #pragma unroll
    for (int i = 0; i < 2; i++){ // stage B tile: 128x32 bf16, 2 x 16B per thread
      int idx = tid + i*256, r = idx >> 2, c = idx & 3;
      uint4 val = *(const uint4*)(Bt + (size_t)r*KP + k0 + c*8);
      *(uint4*)(&Bs[r][c*8]) = val;
    }
    __syncthreads();
    short8 af = *(const short8*)(&As[w*16 + (lane & 15)][(lane >> 4)*8]);
    #pragma unroll
    for (int nt = 0; nt < 8; nt++){
      short8 bf = *(const short8*)(&Bs[nt*16 + (lane & 15)][(lane >> 4)*8]);
      acc[nt] = __builtin_amdgcn_mfma_f32_16x16x32_bf16(af, bf, acc[nt], 0, 0, 0);
    }
    __syncthreads();
  }
  int col = lane & 15, rq = lane >> 4;
  #pragma unroll
  for (int nt = 0; nt < 8; nt++){
    #pragma unroll
    for (int r = 0; r < 4; r++){
      int v = m0 + w*16 + rq*4 + r;
      int j = nt*16 + col;
      if (v < NN){
        float x = opf[(size_t)v*DD + j] + acc[nt][r] * 0.2f;
        out[(size_t)v*DD + j] = x > 0.f ? x : 0.f;
      }
    }
  }
}

extern "C" void kernel_launch(void* const* d_in, const int* in_sizes, int n_in,
                              void* d_out, int out_size, void* d_ws, size_t ws_size,
                              hipStream_t stream){
  const float* opf = (const float*)d_in[0];
  const float* ef[5]; const float* W[5]; const float* bb[5]; const int* sr[5]; const int* ds[5];
  for (int t = 0; t < 5; t++){
    ef[t] = (const float*)d_in[1 + 5*t + 0];
    W [t] = (const float*)d_in[1 + 5*t + 1];
    bb[t] = (const float*)d_in[1 + 5*t + 2];
    sr[t] = (const int*)  d_in[1 + 5*t + 3];
    ds[t] = (const int*)  d_in[1 + 5*t + 4];
  }
  char* ws = (char*)d_ws;
  int* deg   = (int*)(ws);                      // 5N*4 = 1.0 MB
  int* off   = (int*)(ws + (1u<<20));           // 1.0 MB
  int* cur   = (int*)(ws + (2u<<20));           // 1.0 MB
  int* elist = (int*)(ws + (3u<<20));           // 10.0 MB
  u16* A     = (u16*)(ws + 16777216);           // 50000*832*2 = 83.2 MB
  u16* Bt    = (u16*)(ws + 99977216);           // 128*832*2 = 213 KB
  int* cs    = (int*)(ws + 100190208);          // 5*196*4

  hipMemsetAsync(deg, 0, NET*NN*sizeof(int), stream);
  dim3 bE((EE + 255)/256, NET);
  k_hist      <<<bE, 256, 0, stream>>>(ds[0],ds[1],ds[2],ds[3],ds[4], deg);
  k_chunksum  <<<dim3(CHUNKS, NET), 256, 0, stream>>>(deg, cs);
  k_scanchunks<<<NET, 64, 0, stream>>>(cs);
  k_localscan <<<dim3(CHUNKS, NET), 256, 0, stream>>>(deg, cs, off, cur);
  k_scatter   <<<bE, 256, 0, stream>>>(ds[0],ds[1],ds[2],ds[3],ds[4], cur, elist);
  k_gather    <<<dim3(NN/4, NET), 256, 0, stream>>>(opf,
                 ef[0],ef[1],ef[2],ef[3],ef[4],
                 sr[0],sr[1],sr[2],sr[3],sr[4],
                 off, deg, elist, A);
  k_convB     <<<(DD*KP + 255)/256, 256, 0, stream>>>(W[0],W[1],W[2],W[3],W[4],
                 bb[0],bb[1],bb[2],bb[3],bb[4], Bt);
  k_gemm      <<<(NN + 63)/64, 256, 0, stream>>>(A, Bt, opf, (float*)d_out);
}

// Round 2
// 959.317 us; speedup vs baseline: 1.1015x; 1.1015x over previous
//
#include <hip/hip_runtime.h>
#include <hip/hip_bf16.h>

#define NN 50000
#define DD 128
#define DEF 32
#define EE 500000
#define NET 5
#define KP 832        // padded K (805 real: 5*128 H | 5*32 EF | 5 mask/bias)
#define CHUNKS 196    // ceil(50000/256)

typedef unsigned short u16;
typedef unsigned int u32;
using short8 = __attribute__((ext_vector_type(8))) short;
using f32x4  = __attribute__((ext_vector_type(4))) float;

__device__ __forceinline__ u16 f2bf(float f){
  union { float f; u32 u; } v; v.f = f;
  u32 r = v.u + 0x7FFFu + ((v.u >> 16) & 1u);
  return (u16)(r >> 16);
}

// ---------------- CSR build ----------------
__global__ void k_hist(const int* d0,const int* d1,const int* d2,const int* d3,const int* d4,
                       int* __restrict__ deg){
  int et = blockIdx.y;
  const int* dp = et==0?d0:et==1?d1:et==2?d2:et==3?d3:d4;
  int i = blockIdx.x*256 + threadIdx.x;
  if (i < EE) atomicAdd(&deg[et*NN + dp[i]], 1);
}

__global__ void k_chunksum(const int* __restrict__ deg, int* __restrict__ cs){
  int et = blockIdx.y;
  int i = blockIdx.x*256 + threadIdx.x;
  int x = (i < NN) ? deg[et*NN + i] : 0;
  #pragma unroll
  for (int d = 32; d >= 1; d >>= 1) x += __shfl_down(x, d, 64);
  __shared__ int ws4[4];
  int lane = threadIdx.x & 63, w = threadIdx.x >> 6;
  if (lane == 0) ws4[w] = x;
  __syncthreads();
  if (threadIdx.x == 0) cs[et*CHUNKS + blockIdx.x] = ws4[0]+ws4[1]+ws4[2]+ws4[3];
}

__global__ void k_scanchunks(int* cs){
  int et = blockIdx.x;
  int lane = threadIdx.x;   // block = 64
  int run = 0;
  for (int c0 = 0; c0 < CHUNKS; c0 += 64){
    int i = c0 + lane;
    int x = (i < CHUNKS) ? cs[et*CHUNKS + i] : 0;
    int own = x;
    #pragma unroll
    for (int d = 1; d < 64; d <<= 1){ int y = __shfl_up(x, d, 64); if (lane >= d) x += y; }
    int tot = __shfl(x, 63, 64);
    if (i < CHUNKS) cs[et*CHUNKS + i] = run + x - own;
    run += tot;
  }
}

__global__ void k_localscan(const int* __restrict__ deg, const int* __restrict__ cs,
                            int* __restrict__ cur){
  int et = blockIdx.y;
  int i = blockIdx.x*256 + threadIdx.x;
  int lane = threadIdx.x & 63, w = threadIdx.x >> 6;
  int x = (i < NN) ? deg[et*NN + i] : 0;
  int own = x;
  #pragma unroll
  for (int d = 1; d < 64; d <<= 1){ int y = __shfl_up(x, d, 64); if (lane >= d) x += y; }
  __shared__ int ws4[4];
  if (lane == 63) ws4[w] = x;
  __syncthreads();
  int add = cs[et*CHUNKS + blockIdx.x];
  for (int k = 0; k < w; k++) add += ws4[k];
  if (i < NN){ cur[et*NN+i] = x - own + add; }   // exclusive prefix
}

// scatter (src, edge) records sorted by dst — removes one dependent load from gather
__global__ void k_scatter(const int* d0,const int* d1,const int* d2,const int* d3,const int* d4,
                          const int* s0,const int* s1,const int* s2,const int* s3,const int* s4,
                          int* __restrict__ cur, int2* __restrict__ el2){
  int et = blockIdx.y;
  const int* dp = et==0?d0:et==1?d1:et==2?d2:et==3?d3:d4;
  const int* sp = et==0?s0:et==1?s1:et==2?s2:et==3?s3:s4;
  int i = blockIdx.x*256 + threadIdx.x;
  if (i < EE){
    int d = dp[i];
    int pos = atomicAdd(&cur[et*NN + d], 1);
    el2[(size_t)et*EE + pos] = make_int2(sp[i], i);
  }
}

// ------------- per-(etype,node) mean gather → bf16 A row slice -------------
// 8-edge branchless batch: 8 record loads + 8 row loads + 8 ef loads in flight per iter
__global__ __launch_bounds__(256) void k_gather(
    const float* __restrict__ opf,
    const float* e0,const float* e1,const float* e2,const float* e3,const float* e4,
    const int* __restrict__ cur, const int* __restrict__ deg,
    const int2* __restrict__ el2, u16* __restrict__ A)
{
  int et = blockIdx.y;
  const float* efp = et==0?e0:et==1?e1:et==2?e2:et==3?e3:e4;
  int tid = threadIdx.x;
  int lane = tid & 63, w = tid >> 6;
  int v = blockIdx.x*4 + w;               // grid.x = NN/4 -> v < NN exactly
  int dg   = deg[et*NN + v];
  int base = cur[et*NN + v] - dg;         // cur is post-scatter end pointer
  const int2* el = el2 + (size_t)et*EE + base;
  float h0 = 0.f, h1 = 0.f, efa = 0.f;
  for (int i = 0; i < dg; i += 8){
    int2  q[8];
    float wt[8];
    #pragma unroll
    for (int t = 0; t < 8; t++){
      int idx = i + t;
      int ic  = idx < dg ? idx : dg - 1;     // clamped: always in-bounds (dg>=1 here)
      q[t]  = el[ic];
      wt[t] = idx < dg ? 1.f : 0.f;
    }
    #pragma unroll
    for (int t = 0; t < 8; t++){
      float2 r = *((const float2*)(opf + (size_t)q[t].x * DD) + lane);
      float  f = (lane < DEF) ? efp[(size_t)q[t].y * DEF + lane] : 0.f;
      h0  += r.x * wt[t];
      h1  += r.y * wt[t];
      efa += f   * wt[t];
    }
  }
  float sc = dg > 0 ? 1.0f/(float)dg : 0.0f;
  u32 pk = (u32)f2bf(h0*sc) | ((u32)f2bf(h1*sc) << 16);
  *(u32*)(A + (size_t)v*KP + et*DD + 2*lane) = pk;
  if (lane < DEF) A[(size_t)v*KP + 640 + et*DEF + lane] = f2bf(efa*sc);
  if (lane == 0)  A[(size_t)v*KP + 800 + et] = dg > 0 ? (u16)0x3F80 : (u16)0;
}

// ------------- build Bt[j][k] (bf16, transposed, pad rows zeroed) -------------
__global__ void k_convB(const float* W0,const float* W1,const float* W2,const float* W3,const float* W4,
                        const float* b0,const float* b1,const float* b2,const float* b3,const float* b4,
                        u16* __restrict__ Bt){
  int id = blockIdx.x*256 + threadIdx.x;
  if (id >= DD*KP) return;
  int j = id / KP, k = id - j*KP;
  const float* Ws[NET] = {W0,W1,W2,W3,W4};
  const float* bs[NET] = {b0,b1,b2,b3,b4};
  float val = 0.f;
  if (k < 640)      { int et = k >> 7, r = k & 127; val = Ws[et][r*DD + j]; }
  else if (k < 800) { int q = k - 640; int et = q >> 5, r = q & 31; val = Ws[et][(DD + r)*DD + j]; }
  else if (k < 805) { val = bs[k - 800][j]; }
  Bt[(size_t)j*KP + k] = f2bf(val);
}

// ------------- fused GEMM + /5 + residual + ReLU -------------
__global__ __launch_bounds__(256) void k_gemm(const u16* __restrict__ A, const u16* __restrict__ Bt,
                                              const float* __restrict__ opf, float* __restrict__ out){
  __shared__ __align__(16) u16 As[64][40];    // +8 pad: bank-conflict break, 16B-aligned rows
  __shared__ __align__(16) u16 Bs[128][40];
  int tid = threadIdx.x, lane = tid & 63, w = tid >> 6;
  int m0 = blockIdx.x * 64;
  f32x4 acc[8];
  #pragma unroll
  for (int nt = 0; nt < 8; nt++) acc[nt] = (f32x4){0.f,0.f,0.f,0.f};

  for (int kt = 0; kt < 26; kt++){
    int k0 = kt * 32;
    { // stage A tile: 64x32 bf16, 1 x 16B per thread
      int r = tid >> 2, c = tid & 3, row = m0 + r;
      uint4 val = {0u,0u,0u,0u};
      if (row < NN) val = *(const uint4*)(A + (size_t)row*KP + k0 + c*8);
      *(uint4*)(&As[r][c*8]) = val;
    }
    #pragma unroll
    for (int i = 0; i < 2; i++){ // stage B tile: 128x32 bf16, 2 x 16B per thread
      int idx = tid + i*256, r = idx >> 2, c = idx & 3;
      uint4 val = *(const uint4*)(Bt + (size_t)r*KP + k0 + c*8);
      *(uint4*)(&Bs[r][c*8]) = val;
    }
    __syncthreads();
    short8 af = *(const short8*)(&As[w*16 + (lane & 15)][(lane >> 4)*8]);
    #pragma unroll
    for (int nt = 0; nt < 8; nt++){
      short8 bf = *(const short8*)(&Bs[nt*16 + (lane & 15)][(lane >> 4)*8]);
      acc[nt] = __builtin_amdgcn_mfma_f32_16x16x32_bf16(af, bf, acc[nt], 0, 0, 0);
    }
    __syncthreads();
  }
  int col = lane & 15, rq = lane >> 4;
  #pragma unroll
  for (int nt = 0; nt < 8; nt++){
    #pragma unroll
    for (int r = 0; r < 4; r++){
      int v = m0 + w*16 + rq*4 + r;
      int j = nt*16 + col;
      if (v < NN){
        float x = opf[(size_t)v*DD + j] + acc[nt][r] * 0.2f;
        out[(size_t)v*DD + j] = x > 0.f ? x : 0.f;
      }
    }
  }
}

extern "C" void kernel_launch(void* const* d_in, const int* in_sizes, int n_in,
                              void* d_out, int out_size, void* d_ws, size_t ws_size,
                              hipStream_t stream){
  const float* opf = (const float*)d_in[0];
  const float* ef[5]; const float* W[5]; const float* bb[5]; const int* sr[5]; const int* ds[5];
  for (int t = 0; t < 5; t++){
    ef[t] = (const float*)d_in[1 + 5*t + 0];
    W [t] = (const float*)d_in[1 + 5*t + 1];
    bb[t] = (const float*)d_in[1 + 5*t + 2];
    sr[t] = (const int*)  d_in[1 + 5*t + 3];
    ds[t] = (const int*)  d_in[1 + 5*t + 4];
  }
  char* ws = (char*)d_ws;
  int*  deg = (int*) (ws);                      // 5N*4  = 1.00 MB
  int*  cur = (int*) (ws + 1048576);            // 1.00 MB
  int*  cs  = (int*) (ws + 2097152);            // 5*196*4
  int2* el2 = (int2*)(ws + 4194304);            // 2.5M * 8B = 20.0 MB
  u16*  A   = (u16*) (ws + 25165824);           // 50000*832*2 = 83.2 MB
  u16*  Bt  = (u16*) (ws + 108527616);          // 128*832*2 = 213 KB

  hipMemsetAsync(deg, 0, NET*NN*sizeof(int), stream);
  dim3 bE((EE + 255)/256, NET);
  k_hist      <<<bE, 256, 0, stream>>>(ds[0],ds[1],ds[2],ds[3],ds[4], deg);
  k_chunksum  <<<dim3(CHUNKS, NET), 256, 0, stream>>>(deg, cs);
  k_scanchunks<<<NET, 64, 0, stream>>>(cs);
  k_localscan <<<dim3(CHUNKS, NET), 256, 0, stream>>>(deg, cs, cur);
  k_scatter   <<<bE, 256, 0, stream>>>(ds[0],ds[1],ds[2],ds[3],ds[4],
                 sr[0],sr[1],sr[2],sr[3],sr[4], cur, el2);
  k_gather    <<<dim3(NN/4, NET), 256, 0, stream>>>(opf,
                 ef[0],ef[1],ef[2],ef[3],ef[4],
                 cur, deg, el2, A);
  k_convB     <<<(DD*KP + 255)/256, 256, 0, stream>>>(W[0],W[1],W[2],W[3],W[4],
                 bb[0],bb[1],bb[2],bb[3],bb[4], Bt);
  k_gemm      <<<(NN + 63)/64, 256, 0, stream>>>(A, Bt, opf, (float*)d_out);
}

// Round 3
// 789.672 us; speedup vs baseline: 1.3381x; 1.2148x over previous
//
#include <hip/hip_runtime.h>
#include <hip/hip_bf16.h>

#define NN 50000
#define DD 128
#define DEF 32
#define EE 500000
#define NET 5
#define KP 832        // padded K (805 real: 5*128 H | 5*32 EF | 5 mask/bias)
#define CHUNKS 196    // ceil(50000/256)

typedef unsigned short u16;
typedef unsigned int u32;
using short8 = __attribute__((ext_vector_type(8))) short;
using f32x4  = __attribute__((ext_vector_type(4))) float;

__device__ __forceinline__ u16 f2bf(float f){
  union { float f; u32 u; } v; v.f = f;
  u32 r = v.u + 0x7FFFu + ((v.u >> 16) & 1u);
  return (u16)(r >> 16);
}

// ---------------- fp32 -> bf16 cast of op_feats ----------------
__global__ void k_cast(const float* __restrict__ x, u16* __restrict__ y){
  int i = blockIdx.x*256 + threadIdx.x;     // grid covers NN*DD/4 exactly
  float4 v = ((const float4*)x)[i];
  ushort4 o; o.x=f2bf(v.x); o.y=f2bf(v.y); o.z=f2bf(v.z); o.w=f2bf(v.w);
  ((ushort4*)y)[i] = o;
}

// ---------------- CSR build ----------------
__global__ void k_hist(const int* d0,const int* d1,const int* d2,const int* d3,const int* d4,
                       int* __restrict__ deg){
  int et = blockIdx.y;
  const int* dp = et==0?d0:et==1?d1:et==2?d2:et==3?d3:d4;
  int i = blockIdx.x*256 + threadIdx.x;
  if (i < EE) atomicAdd(&deg[et*NN + dp[i]], 1);
}

__global__ void k_chunksum(const int* __restrict__ deg, int* __restrict__ cs){
  int et = blockIdx.y;
  int i = blockIdx.x*256 + threadIdx.x;
  int x = (i < NN) ? deg[et*NN + i] : 0;
  #pragma unroll
  for (int d = 32; d >= 1; d >>= 1) x += __shfl_down(x, d, 64);
  __shared__ int ws4[4];
  int lane = threadIdx.x & 63, w = threadIdx.x >> 6;
  if (lane == 0) ws4[w] = x;
  __syncthreads();
  if (threadIdx.x == 0) cs[et*CHUNKS + blockIdx.x] = ws4[0]+ws4[1]+ws4[2]+ws4[3];
}

__global__ void k_scanchunks(int* cs){
  int et = blockIdx.x;
  int lane = threadIdx.x;   // block = 64
  int run = 0;
  for (int c0 = 0; c0 < CHUNKS; c0 += 64){
    int i = c0 + lane;
    int x = (i < CHUNKS) ? cs[et*CHUNKS + i] : 0;
    int own = x;
    #pragma unroll
    for (int d = 1; d < 64; d <<= 1){ int y = __shfl_up(x, d, 64); if (lane >= d) x += y; }
    int tot = __shfl(x, 63, 64);
    if (i < CHUNKS) cs[et*CHUNKS + i] = run + x - own;
    run += tot;
  }
}

__global__ void k_localscan(const int* __restrict__ deg, const int* __restrict__ cs,
                            int* __restrict__ cur){
  int et = blockIdx.y;
  int i = blockIdx.x*256 + threadIdx.x;
  int lane = threadIdx.x & 63, w = threadIdx.x >> 6;
  int x = (i < NN) ? deg[et*NN + i] : 0;
  int own = x;
  #pragma unroll
  for (int d = 1; d < 64; d <<= 1){ int y = __shfl_up(x, d, 64); if (lane >= d) x += y; }
  __shared__ int ws4[4];
  if (lane == 63) ws4[w] = x;
  __syncthreads();
  int add = cs[et*CHUNKS + blockIdx.x];
  for (int k = 0; k < w; k++) add += ws4[k];
  if (i < NN){ cur[et*NN+i] = x - own + add; }   // exclusive prefix
}

// scatter (src, edge) records sorted by dst
__global__ void k_scatter(const int* d0,const int* d1,const int* d2,const int* d3,const int* d4,
                          const int* s0,const int* s1,const int* s2,const int* s3,const int* s4,
                          int* __restrict__ cur, int2* __restrict__ el2){
  int et = blockIdx.y;
  const int* dp = et==0?d0:et==1?d1:et==2?d2:et==3?d3:d4;
  const int* sp = et==0?s0:et==1?s1:et==2?s2:et==3?s3:s4;
  int i = blockIdx.x*256 + threadIdx.x;
  if (i < EE){
    int d = dp[i];
    int pos = atomicAdd(&cur[et*NN + d], 1);
    el2[(size_t)et*EE + pos] = make_int2(sp[i], i);
  }
}

// ------------- per-(etype,node) mean gather (bf16 rows) → bf16 A row slice -------------
// batch 16 with explicit phase separation: 1 coalesced record load + shfl broadcast,
// 16 independent bf16-row loads, 8 ef loads (even/odd split across wave halves).
__global__ __launch_bounds__(256) void k_gather(
    const u16* __restrict__ opb,
    const float* e0,const float* e1,const float* e2,const float* e3,const float* e4,
    const int* __restrict__ cur, const int* __restrict__ deg,
    const int2* __restrict__ el2, u16* __restrict__ A)
{
  int et = blockIdx.y;
  const float* efp = et==0?e0:et==1?e1:et==2?e2:et==3?e3:e4;
  int tid = threadIdx.x;
  int lane = tid & 63, w = tid >> 6;
  int v = blockIdx.x*4 + w;               // grid.x = NN/4 -> v < NN exactly
  int dg   = deg[et*NN + v];
  int base = cur[et*NN + v] - dg;         // cur is post-scatter end pointer
  const int2* el = el2 + (size_t)et*EE + base;
  int laneh = lane & 31;
  int hi = lane >> 5;                     // 0 for lanes 0-31, 1 for 32-63
  float h0 = 0.f, h1 = 0.f, efa = 0.f;
  for (int i0 = 0; i0 < dg; i0 += 16){
    // phase 1: one coalesced 128B record load (16 records replicated 4x across wave)
    int li  = i0 + (lane & 15);
    int lic = li < dg ? li : dg - 1;
    int2 rec = el[lic];
    int sL[16], eL[8];
    #pragma unroll
    for (int t = 0; t < 16; t++) sL[t] = __shfl(rec.x, t, 16);
    #pragma unroll
    for (int p = 0; p < 8; p++)  eL[p] = __shfl(rec.y, 2*p + hi, 16);
    // phase 2: 16 independent row loads (4B/lane, 256B/row coalesced)
    u32 rv[16];
    #pragma unroll
    for (int t = 0; t < 16; t++)
      rv[t] = *((const u32*)(opb + (size_t)sL[t]*DD) + lane);
    // phase 3: 8 ef loads, all 64 lanes busy (low half: even t, high half: odd t)
    float fv[8];
    #pragma unroll
    for (int p = 0; p < 8; p++)
      fv[p] = __builtin_nontemporal_load(&efp[(size_t)eL[p]*DEF + laneh]);
    // phase 4: reduce
    #pragma unroll
    for (int t = 0; t < 16; t++){
      float wt = (i0 + t < dg) ? 1.f : 0.f;
      union {u32 u; float f;} a, b;
      a.u = rv[t] << 16; b.u = rv[t] & 0xFFFF0000u;
      h0 += a.f * wt; h1 += b.f * wt;
    }
    #pragma unroll
    for (int p = 0; p < 8; p++){
      float wt = (i0 + 2*p + hi < dg) ? 1.f : 0.f;
      efa += fv[p] * wt;
    }
  }
  efa += __shfl(efa, lane ^ 32, 64);      // combine even/odd halves
  float sc = dg > 0 ? 1.0f/(float)dg : 0.0f;
  u32 pk = (u32)f2bf(h0*sc) | ((u32)f2bf(h1*sc) << 16);
  *(u32*)(A + (size_t)v*KP + et*DD + 2*lane) = pk;
  if (lane < DEF) A[(size_t)v*KP + 640 + et*DEF + lane] = f2bf(efa*sc);
  if (lane == 0)  A[(size_t)v*KP + 800 + et] = dg > 0 ? (u16)0x3F80 : (u16)0;
}

// ------------- build Bt[j][k] (bf16, transposed, pad rows zeroed) -------------
__global__ void k_convB(const float* W0,const float* W1,const float* W2,const float* W3,const float* W4,
                        const float* b0,const float* b1,const float* b2,const float* b3,const float* b4,
                        u16* __restrict__ Bt){
  int id = blockIdx.x*256 + threadIdx.x;
  if (id >= DD*KP) return;
  int j = id / KP, k = id - j*KP;
  const float* Ws[NET] = {W0,W1,W2,W3,W4};
  const float* bs[NET] = {b0,b1,b2,b3,b4};
  float val = 0.f;
  if (k < 640)      { int et = k >> 7, r = k & 127; val = Ws[et][r*DD + j]; }
  else if (k < 800) { int q = k - 640; int et = q >> 5, r = q & 31; val = Ws[et][(DD + r)*DD + j]; }
  else if (k < 805) { val = bs[k - 800][j]; }
  Bt[(size_t)j*KP + k] = f2bf(val);
}

// ------------- fused GEMM + /5 + residual + ReLU (128-row tiles) -------------
__global__ __launch_bounds__(256) void k_gemm(const u16* __restrict__ A, const u16* __restrict__ Bt,
                                              const float* __restrict__ opf, float* __restrict__ out){
  __shared__ __align__(16) u16 As[128][40];   // +8 pad breaks power-of-2 stride
  __shared__ __align__(16) u16 Bs[128][40];
  int tid = threadIdx.x, lane = tid & 63, w = tid >> 6;
  int m0 = blockIdx.x * 128;
  f32x4 acc[2][8];
  #pragma unroll
  for (int mh = 0; mh < 2; mh++)
    #pragma unroll
    for (int nt = 0; nt < 8; nt++) acc[mh][nt] = (f32x4){0.f,0.f,0.f,0.f};

  for (int kt = 0; kt < 26; kt++){
    int k0 = kt * 32;
    #pragma unroll
    for (int i = 0; i < 2; i++){    // stage A(128x32) + B(128x32), 2 x 16B each per thread
      int idx = tid + i*256, r = idx >> 2, c = idx & 3;
      int row = m0 + r;
      uint4 va = {0u,0u,0u,0u};
      if (row < NN) va = *(const uint4*)(A + (size_t)row*KP + k0 + c*8);
      *(uint4*)(&As[r][c*8]) = va;
      uint4 vb = *(const uint4*)(Bt + (size_t)r*KP + k0 + c*8);
      *(uint4*)(&Bs[r][c*8]) = vb;
    }
    __syncthreads();
    short8 af0 = *(const short8*)(&As[w*32      + (lane & 15)][(lane >> 4)*8]);
    short8 af1 = *(const short8*)(&As[w*32 + 16 + (lane & 15)][(lane >> 4)*8]);
    #pragma unroll
    for (int nt = 0; nt < 8; nt++){
      short8 bf = *(const short8*)(&Bs[nt*16 + (lane & 15)][(lane >> 4)*8]);
      acc[0][nt] = __builtin_amdgcn_mfma_f32_16x16x32_bf16(af0, bf, acc[0][nt], 0, 0, 0);
      acc[1][nt] = __builtin_amdgcn_mfma_f32_16x16x32_bf16(af1, bf, acc[1][nt], 0, 0, 0);
    }
    __syncthreads();
  }
  int col = lane & 15, rq = lane >> 4;
  #pragma unroll
  for (int mh = 0; mh < 2; mh++){
    #pragma unroll
    for (int nt = 0; nt < 8; nt++){
      #pragma unroll
      for (int r = 0; r < 4; r++){
        int v = m0 + w*32 + mh*16 + rq*4 + r;
        int j = nt*16 + col;
        if (v < NN){
          float x = opf[(size_t)v*DD + j] + acc[mh][nt][r] * 0.2f;
          out[(size_t)v*DD + j] = x > 0.f ? x : 0.f;
        }
      }
    }
  }
}

extern "C" void kernel_launch(void* const* d_in, const int* in_sizes, int n_in,
                              void* d_out, int out_size, void* d_ws, size_t ws_size,
                              hipStream_t stream){
  const float* opf = (const float*)d_in[0];
  const float* ef[5]; const float* W[5]; const float* bb[5]; const int* sr[5]; const int* ds[5];
  for (int t = 0; t < 5; t++){
    ef[t] = (const float*)d_in[1 + 5*t + 0];
    W [t] = (const float*)d_in[1 + 5*t + 1];
    bb[t] = (const float*)d_in[1 + 5*t + 2];
    sr[t] = (const int*)  d_in[1 + 5*t + 3];
    ds[t] = (const int*)  d_in[1 + 5*t + 4];
  }
  char* ws = (char*)d_ws;
  int*  deg = (int*) (ws);                      // 1,000,000 B
  int*  cur = (int*) (ws + 1000000);            // 1,000,000 B
  int*  cs  = (int*) (ws + 2000000);            // 3,920 B
  u16*  Bt  = (u16*) (ws + 2004992);            // 212,992 B
  u16*  opb = (u16*) (ws + 2220032);            // 12,800,000 B
  int2* el2 = (int2*)(ws + 15020032);           // 20,000,000 B
  u16*  A   = (u16*) (ws + 35020032);           // 83,200,000 B  (total ~118.2 MB)

  hipMemsetAsync(deg, 0, NET*NN*sizeof(int), stream);
  dim3 bE((EE + 255)/256, NET);
  k_cast      <<<NN*DD/4/256, 256, 0, stream>>>(opf, opb);
  k_hist      <<<bE, 256, 0, stream>>>(ds[0],ds[1],ds[2],ds[3],ds[4], deg);
  k_chunksum  <<<dim3(CHUNKS, NET), 256, 0, stream>>>(deg, cs);
  k_scanchunks<<<NET, 64, 0, stream>>>(cs);
  k_localscan <<<dim3(CHUNKS, NET), 256, 0, stream>>>(deg, cs, cur);
  k_scatter   <<<bE, 256, 0, stream>>>(ds[0],ds[1],ds[2],ds[3],ds[4],
                 sr[0],sr[1],sr[2],sr[3],sr[4], cur, el2);
  k_gather    <<<dim3(NN/4, NET), 256, 0, stream>>>(opb,
                 ef[0],ef[1],ef[2],ef[3],ef[4],
                 cur, deg, el2, A);
  k_convB     <<<(DD*KP + 255)/256, 256, 0, stream>>>(W[0],W[1],W[2],W[3],W[4],
                 bb[0],bb[1],bb[2],bb[3],bb[4], Bt);
  k_gemm      <<<(NN + 127)/128, 256, 0, stream>>>(A, Bt, opf, (float*)d_out);
}